// Round 5
// baseline (1129.180 us; speedup 1.0000x reference)
//
#include <hip/hip_runtime.h>
#include <hip/hip_bf16.h>

#define S 17
#define NPOS 4096
#define D 256
#define NH 8
#define CH 32
#define MROWS 16

__device__ __forceinline__ float bfu(unsigned short u) {
  return __uint_as_float(((unsigned int)u) << 16);
}
__device__ __forceinline__ unsigned short f2b(float f) {
  __hip_bfloat16 t = __float2bfloat16(f);
  return *reinterpret_cast<unsigned short*>(&t);
}
__device__ __forceinline__ void unpack16(const uint4 A, const uint4 B, float* r) {
  r[0]  = __uint_as_float(A.x << 16); r[1]  = __uint_as_float(A.x & 0xffff0000u);
  r[2]  = __uint_as_float(A.y << 16); r[3]  = __uint_as_float(A.y & 0xffff0000u);
  r[4]  = __uint_as_float(A.z << 16); r[5]  = __uint_as_float(A.z & 0xffff0000u);
  r[6]  = __uint_as_float(A.w << 16); r[7]  = __uint_as_float(A.w & 0xffff0000u);
  r[8]  = __uint_as_float(B.x << 16); r[9]  = __uint_as_float(B.x & 0xffff0000u);
  r[10] = __uint_as_float(B.y << 16); r[11] = __uint_as_float(B.y & 0xffff0000u);
  r[12] = __uint_as_float(B.z << 16); r[13] = __uint_as_float(B.z & 0xffff0000u);
  r[14] = __uint_as_float(B.w << 16); r[15] = __uint_as_float(B.w & 0xffff0000u);
}

struct TensorList {
  const unsigned short* p[8];
  int n[8];
};

// Per-tensor dtype detection. flags[b]=1 -> f32 storage, 0 -> bf16 storage.
__global__ void detect_multi_kernel(TensorList tl, int* __restrict__ flags) {
  __shared__ int s_totnz, s_evnz, s_evwild;
  if (threadIdx.x == 0) { s_totnz = 0; s_evnz = 0; s_evwild = 0; }
  __syncthreads();
  const unsigned short* p = tl.p[blockIdx.x];
  const int n = tl.n[blockIdx.x];
  const int w = n < 4096 ? n : 4096;
  int totnz = 0, evnz = 0, evwild = 0;
  for (int i = threadIdx.x; i < w; i += blockDim.x) {
    unsigned short u = p[i];
    if (u) {
      totnz++;
      if (!(i & 1)) {
        evnz++;
        int e = (u >> 7) & 0xFF;
        if (e == 0 || e == 255 || e < 97 || e > 157) evwild++;
      }
    }
  }
  atomicAdd(&s_totnz, totnz);
  atomicAdd(&s_evnz, evnz);
  atomicAdd(&s_evwild, evwild);
  __syncthreads();
  if (threadIdx.x == 0) {
    const int evcount = w / 2;
    int f;
    if (s_totnz == 0) f = 0;
    else if (s_evnz == 0) f = 1;
    else if (s_evwild * 8 > evcount) f = 1;
    else f = 0;
    flags[blockIdx.x] = f;
  }
}

// ---- mask dtype classification: 0=i32, 1=u8, 2=f32, 3=bf16, 4=i64 ----
__global__ void detect_mask_kernel(const unsigned int* __restrict__ w,
                                   int* __restrict__ cls) {
  __shared__ int viol[5];
  if (threadIdx.x < 5) viol[threadIdx.x] = 0;
  __syncthreads();
  int v_i32 = 0, v_f32 = 0, v_bf16 = 0, v_u8 = 0, v_i64 = 0;
  const int nwords = 65536 / 4;
  for (int i = threadIdx.x; i < nwords; i += blockDim.x) {
    unsigned int x = w[i];
    if (x > 1u) v_i32 = 1;
    if (x != 0u && x != 0x3F800000u) v_f32 = 1;
    unsigned int lo = x & 0xFFFFu, hi = x >> 16;
    if ((lo != 0u && lo != 0x3F80u) || (hi != 0u && hi != 0x3F80u)) v_bf16 = 1;
    if ((x & 0xFEFEFEFEu) != 0u) v_u8 = 1;
    if ((i & 1) && x != 0u) v_i64 = 1;
  }
  if (v_i32) atomicOr(&viol[0], 1);
  if (v_f32) atomicOr(&viol[1], 1);
  if (v_bf16) atomicOr(&viol[2], 1);
  if (v_u8) atomicOr(&viol[3], 1);
  if (v_i64) atomicOr(&viol[4], 1);
  __syncthreads();
  if (threadIdx.x == 0) {
    int c;
    if (!viol[0] && !viol[4]) c = 4;
    else if (!viol[0]) c = 0;
    else if (!viol[1]) c = 2;
    else if (!viol[2]) c = 3;
    else c = 1;
    *cls = c;
  }
}

// mask_u8[0][n] = any over rows (cols); mask_u8[1+m][n] = target_msta_mask[m][n]
__global__ void expand_mask_kernel(const void* __restrict__ tmask, const int* __restrict__ cls,
                                   unsigned char* __restrict__ mask_u8) {
  int n = blockIdx.x * blockDim.x + threadIdx.x;
  if (n >= NPOS) return;
  const int c = *cls;
  int any = 0;
  for (int m = 0; m < MROWS; m++) {
    size_t idx = (size_t)m * NPOS + n;
    int v;
    if (c == 0)      v = ((const int*)tmask)[idx] != 0;
    else if (c == 1) v = ((const unsigned char*)tmask)[idx] != 0;
    else if (c == 2) v = ((const unsigned int*)tmask)[idx] != 0u;
    else if (c == 3) v = ((const unsigned short*)tmask)[idx] != 0u;
    else             v = ((const unsigned long long*)tmask)[idx] != 0ull;
    mask_u8[(m + 1) * NPOS + n] = (unsigned char)v;
    any |= v;
  }
  mask_u8[n] = (unsigned char)any;
}

// acc[s] = sum_d in[s][d] * W[tid][d]; IN: LDS (bf16 bits or f32), W: global per WF32
template <int WF32, int INF32>
__device__ __forceinline__ void gemm17_t(const void* inb,
                                         const void* __restrict__ Wg,
                                         int tid, float* acc) {
  #pragma unroll
  for (int s = 0; s < S; s++) acc[s] = 0.f;
  #pragma unroll 2
  for (int kt = 0; kt < 16; ++kt) {
    float wr[16];
    if (WF32) {
      const float4* wp = (const float4*)((const float*)Wg + tid * D + kt * 16);
      float4 w0 = wp[0], w1 = wp[1], w2 = wp[2], w3 = wp[3];
      wr[0] = w0.x; wr[1] = w0.y; wr[2] = w0.z; wr[3] = w0.w;
      wr[4] = w1.x; wr[5] = w1.y; wr[6] = w1.z; wr[7] = w1.w;
      wr[8] = w2.x; wr[9] = w2.y; wr[10] = w2.z; wr[11] = w2.w;
      wr[12] = w3.x; wr[13] = w3.y; wr[14] = w3.z; wr[15] = w3.w;
    } else {
      const uint4* wp = (const uint4*)((const unsigned short*)Wg + tid * D + kt * 16);
      unpack16(wp[0], wp[1], wr);
    }
    #pragma unroll
    for (int s = 0; s < S; s++) {
      float hr[16];
      if (INF32) {
        const float4* hp = (const float4*)((const float*)inb + s * D + kt * 16);
        float4 a0 = hp[0], a1 = hp[1], a2 = hp[2], a3 = hp[3];
        hr[0] = a0.x; hr[1] = a0.y; hr[2] = a0.z; hr[3] = a0.w;
        hr[4] = a1.x; hr[5] = a1.y; hr[6] = a1.z; hr[7] = a1.w;
        hr[8] = a2.x; hr[9] = a2.y; hr[10] = a2.z; hr[11] = a2.w;
        hr[12] = a3.x; hr[13] = a3.y; hr[14] = a3.z; hr[15] = a3.w;
      } else {
        const uint4* hp = (const uint4*)((const unsigned short*)inb + s * D + kt * 16);
        unpack16(hp[0], hp[1], hr);
      }
      float a = 0.f;
      #pragma unroll
      for (int u = 0; u < 16; u++) a = fmaf(hr[u], wr[u], a);
      acc[s] += a;
    }
  }
}

template <int INF32>
__device__ __forceinline__ void gemm17(const void* inb, const void* __restrict__ Wg,
                                       int wf32, int tid, float* acc) {
  if (wf32) gemm17_t<1, INF32>(inb, Wg, tid, acc);
  else      gemm17_t<0, INF32>(inb, Wg, tid, acc);
}

__device__ __forceinline__ float readv(const void* p, int f32, size_t i) {
  return f32 ? ((const float*)p)[i] : bfu(((const unsigned short*)p)[i]);
}

template <int HF32>
__device__ __forceinline__ void run_body(
    const void* __restrict__ h, const unsigned char* __restrict__ mask_u8,
    const int* __restrict__ fl,
    const void* __restrict__ Wq, const void* __restrict__ Wk,
    const void* __restrict__ Wv, const void* __restrict__ Wo,
    const void* __restrict__ bo, const void* __restrict__ lng,
    const void* __restrict__ lnb, float* __restrict__ out,
    unsigned short* hb, unsigned short* qb, unsigned short* kb, unsigned short* vb,
    float* ob, float* attw, float* redbuf, unsigned char* smask) {
  const int tid = threadIdx.x;
  const int n = blockIdx.x;
  const int fWq = fl[1], fWk = fl[2], fWv = fl[3], fWo = fl[4];

  if (tid < S) smask[tid] = mask_u8[tid * NPOS + n];
  if (HF32) {
    for (int i = tid; i < S * (D / 4); i += 256) {
      int s = i >> 6, dv = i & 63;
      float4 v = ((const float4*)h)[(size_t)(s * NPOS + n) * (D / 4) + dv];
      hb[s * D + dv * 4 + 0] = f2b(v.x);
      hb[s * D + dv * 4 + 1] = f2b(v.y);
      hb[s * D + dv * 4 + 2] = f2b(v.z);
      hb[s * D + dv * 4 + 3] = f2b(v.w);
    }
  } else {
    for (int i = tid; i < S * (D / 8); i += 256) {
      int s = i >> 5, dv = i & 31;
      ((uint4*)hb)[i] = ((const uint4*)h)[(size_t)(s * NPOS + n) * (D / 8) + dv];
    }
  }
  __syncthreads();

  float acc[S];
  gemm17<0>(hb, Wq, fWq, tid, acc);
  #pragma unroll
  for (int s = 0; s < S; s++) qb[s * D + tid] = f2b(acc[s]);
  gemm17<0>(hb, Wk, fWk, tid, acc);
  #pragma unroll
  for (int s = 0; s < S; s++) kb[s * D + tid] = f2b(acc[s]);
  gemm17<0>(hb, Wv, fWv, tid, acc);
  #pragma unroll
  for (int s = 0; s < S; s++) vb[s * D + tid] = f2b(acc[s]);
  __syncthreads();

  const float scale = 0.17677669529663687f;  // 1/sqrt(32)
  for (int s = 0; s < S; s++) {
    if (tid < NH * S) {
      const int hh = tid / S, t_ = tid % S;
      float a = 0.f;
      #pragma unroll
      for (int c = 0; c < CH; c++) {
        const int cc = (c + tid) & (CH - 1);
        a = fmaf(bfu(qb[s * D + hh * CH + cc]), bfu(kb[t_ * D + hh * CH + cc]), a);
      }
      a *= scale;
      if (!smask[t_]) a -= 1e9f;  // exp underflows to exactly 0, matching np ref
      attw[hh * S + t_] = a;
    }
    __syncthreads();
    if (tid < NH) {
      float m = -3.4e38f;
      #pragma unroll
      for (int t_ = 0; t_ < S; t_++) m = fmaxf(m, attw[tid * S + t_]);
      float e[S];
      float sum = 0.f;
      #pragma unroll
      for (int t_ = 0; t_ < S; t_++) { e[t_] = __expf(attw[tid * S + t_] - m); sum += e[t_]; }
      const float inv = 1.f / sum;
      #pragma unroll
      for (int t_ = 0; t_ < S; t_++) attw[tid * S + t_] = e[t_] * inv;
    }
    __syncthreads();
    {
      const int hh = tid >> 5;
      float ov = 0.f;
      #pragma unroll
      for (int t_ = 0; t_ < S; t_++) ov = fmaf(attw[hh * S + t_], bfu(vb[t_ * D + tid]), ov);
      // o = mask ? attn_o : h@Wv^T (vb holds exactly the unmasked projection)
      ob[s * D + tid] = smask[s] ? ov : bfu(vb[s * D + tid]);
    }
    __syncthreads();
  }

  float acc2[S];
  gemm17<1>(ob, Wo, fWo, tid, acc2);

  const float g  = readv(lng, fl[6], tid);
  const float bb = readv(lnb, fl[7], tid);
  const float bv = readv(bo,  fl[5], tid);
  for (int s = 0; s < S; s++) {
    // full-precision h for the residual+LN (avoid bf16-rounded hb here)
    const float hval = readv(h, HF32, (size_t)(s * NPOS + n) * D + tid);
    const float x = hval + acc2[s] + bv;
    float ssum = x, ssq = x * x;
    #pragma unroll
    for (int off = 32; off > 0; off >>= 1) {
      ssum += __shfl_down(ssum, off, 64);
      ssq += __shfl_down(ssq, off, 64);
    }
    if ((tid & 63) == 0) {
      redbuf[(tid >> 6) * 2] = ssum;
      redbuf[(tid >> 6) * 2 + 1] = ssq;
    }
    __syncthreads();
    const float tsum = redbuf[0] + redbuf[2] + redbuf[4] + redbuf[6];
    const float tsq = redbuf[1] + redbuf[3] + redbuf[5] + redbuf[7];
    const float mu = tsum * (1.0f / D);
    const float var = fmaxf(tsq * (1.0f / D) - mu * mu, 0.0f);
    const float y = (x - mu) * rsqrtf(var + 1e-5f) * g + bb;
    out[(size_t)(s * NPOS + n) * D + tid] = y;  // f32 store: output dtype is float32
    __syncthreads();
  }
}

__global__ __launch_bounds__(256) void fused_msta_kernel(
    const void* __restrict__ h, const unsigned char* __restrict__ mask_u8,
    const int* __restrict__ flags,
    const void* __restrict__ Wq, const void* __restrict__ Wk,
    const void* __restrict__ Wv, const void* __restrict__ Wo,
    const void* __restrict__ bo, const void* __restrict__ lng,
    const void* __restrict__ lnb, float* __restrict__ out) {
  __shared__ __align__(16) unsigned short hb[S * D];
  __shared__ __align__(16) unsigned short qb[S * D];
  __shared__ __align__(16) unsigned short kb[S * D];
  __shared__ __align__(16) unsigned short vb[S * D];
  __shared__ __align__(16) float ob[S * D];
  __shared__ float attw[NH * S];
  __shared__ float redbuf[8];
  __shared__ unsigned char smask[32];

  if (flags[0])
    run_body<1>(h, mask_u8, flags, Wq, Wk, Wv, Wo, bo, lng, lnb, out,
                hb, qb, kb, vb, ob, attw, redbuf, smask);
  else
    run_body<0>(h, mask_u8, flags, Wq, Wk, Wv, Wo, bo, lng, lnb, out,
                hb, qb, kb, vb, ob, attw, redbuf, smask);
}

extern "C" void kernel_launch(void* const* d_in, const int* in_sizes, int n_in,
                              void* d_out, int out_size, void* d_ws, size_t ws_size,
                              hipStream_t stream) {
  const void* h     = d_in[0];
  const void* tmask = d_in[1];
  const void* Wq  = d_in[3];
  const void* Wk  = d_in[4];
  const void* Wv  = d_in[5];
  const void* Wo  = d_in[6];
  const void* bo  = d_in[7];
  const void* lng = d_in[8];
  const void* lnb = d_in[9];
  float* out = (float*)d_out;

  int* mcls  = (int*)d_ws;
  int* flags = (int*)((char*)d_ws + 64);
  unsigned char* mask_u8 = (unsigned char*)d_ws + 128;

  TensorList tl;
  tl.p[0] = (const unsigned short*)h;   tl.n[0] = in_sizes[0];
  tl.p[1] = (const unsigned short*)Wq;  tl.n[1] = in_sizes[3];
  tl.p[2] = (const unsigned short*)Wk;  tl.n[2] = in_sizes[4];
  tl.p[3] = (const unsigned short*)Wv;  tl.n[3] = in_sizes[5];
  tl.p[4] = (const unsigned short*)Wo;  tl.n[4] = in_sizes[6];
  tl.p[5] = (const unsigned short*)bo;  tl.n[5] = in_sizes[7];
  tl.p[6] = (const unsigned short*)lng; tl.n[6] = in_sizes[8];
  tl.p[7] = (const unsigned short*)lnb; tl.n[7] = in_sizes[9];

  detect_multi_kernel<<<8, 256, 0, stream>>>(tl, flags);
  detect_mask_kernel<<<1, 256, 0, stream>>>((const unsigned int*)tmask, mcls);
  expand_mask_kernel<<<NPOS / 256, 256, 0, stream>>>(tmask, mcls, mask_u8);
  fused_msta_kernel<<<NPOS, 256, 0, stream>>>(h, mask_u8, flags, Wq, Wk, Wv, Wo,
                                              bo, lng, lnb, out);
}

// Round 6
// 639.957 us; speedup vs baseline: 1.7645x; 1.7645x over previous
//
#include <hip/hip_runtime.h>
#include <hip/hip_bf16.h>

#define S 17
#define NPOS 4096
#define D 256
#define NH 8
#define CH 32
#define MROWS 16

typedef __attribute__((ext_vector_type(8))) short bf16x8;
typedef __attribute__((ext_vector_type(4))) float f32x4;

__device__ __forceinline__ float bfu(unsigned short u) {
  return __uint_as_float(((unsigned int)u) << 16);
}
__device__ __forceinline__ unsigned short f2b(float f) {
  __hip_bfloat16 t = __float2bfloat16(f);
  return *reinterpret_cast<unsigned short*>(&t);
}
__device__ __forceinline__ void unpack16(const uint4 A, const uint4 B, float* r) {
  r[0]  = __uint_as_float(A.x << 16); r[1]  = __uint_as_float(A.x & 0xffff0000u);
  r[2]  = __uint_as_float(A.y << 16); r[3]  = __uint_as_float(A.y & 0xffff0000u);
  r[4]  = __uint_as_float(A.z << 16); r[5]  = __uint_as_float(A.z & 0xffff0000u);
  r[6]  = __uint_as_float(A.w << 16); r[7]  = __uint_as_float(A.w & 0xffff0000u);
  r[8]  = __uint_as_float(B.x << 16); r[9]  = __uint_as_float(B.x & 0xffff0000u);
  r[10] = __uint_as_float(B.y << 16); r[11] = __uint_as_float(B.y & 0xffff0000u);
  r[12] = __uint_as_float(B.z << 16); r[13] = __uint_as_float(B.z & 0xffff0000u);
  r[14] = __uint_as_float(B.w << 16); r[15] = __uint_as_float(B.w & 0xffff0000u);
}
__device__ __forceinline__ float readv(const void* p, int f32, size_t i) {
  return f32 ? ((const float*)p)[i] : bfu(((const unsigned short*)p)[i]);
}

struct TensorList {
  const unsigned short* p[8];
  int n[8];
};

// Per-tensor dtype detection. flags[b]=1 -> f32 storage, 0 -> bf16 storage. (proven r5)
__global__ void detect_multi_kernel(TensorList tl, int* __restrict__ flags) {
  __shared__ int s_totnz, s_evnz, s_evwild;
  if (threadIdx.x == 0) { s_totnz = 0; s_evnz = 0; s_evwild = 0; }
  __syncthreads();
  const unsigned short* p = tl.p[blockIdx.x];
  const int n = tl.n[blockIdx.x];
  const int w = n < 4096 ? n : 4096;
  int totnz = 0, evnz = 0, evwild = 0;
  for (int i = threadIdx.x; i < w; i += blockDim.x) {
    unsigned short u = p[i];
    if (u) {
      totnz++;
      if (!(i & 1)) {
        evnz++;
        int e = (u >> 7) & 0xFF;
        if (e == 0 || e == 255 || e < 97 || e > 157) evwild++;
      }
    }
  }
  atomicAdd(&s_totnz, totnz);
  atomicAdd(&s_evnz, evnz);
  atomicAdd(&s_evwild, evwild);
  __syncthreads();
  if (threadIdx.x == 0) {
    const int evcount = w / 2;
    int f;
    if (s_totnz == 0) f = 0;
    else if (s_evnz == 0) f = 1;
    else if (s_evwild * 8 > evcount) f = 1;
    else f = 0;
    flags[blockIdx.x] = f;
  }
}

// mask dtype classification: 0=i32, 1=u8, 2=f32, 3=bf16, 4=i64 (proven r5)
__global__ void detect_mask_kernel(const unsigned int* __restrict__ w,
                                   int* __restrict__ cls) {
  __shared__ int viol[5];
  if (threadIdx.x < 5) viol[threadIdx.x] = 0;
  __syncthreads();
  int v_i32 = 0, v_f32 = 0, v_bf16 = 0, v_u8 = 0, v_i64 = 0;
  const int nwords = 65536 / 4;
  for (int i = threadIdx.x; i < nwords; i += blockDim.x) {
    unsigned int x = w[i];
    if (x > 1u) v_i32 = 1;
    if (x != 0u && x != 0x3F800000u) v_f32 = 1;
    unsigned int lo = x & 0xFFFFu, hi = x >> 16;
    if ((lo != 0u && lo != 0x3F80u) || (hi != 0u && hi != 0x3F80u)) v_bf16 = 1;
    if ((x & 0xFEFEFEFEu) != 0u) v_u8 = 1;
    if ((i & 1) && x != 0u) v_i64 = 1;
  }
  if (v_i32) atomicOr(&viol[0], 1);
  if (v_f32) atomicOr(&viol[1], 1);
  if (v_bf16) atomicOr(&viol[2], 1);
  if (v_u8) atomicOr(&viol[3], 1);
  if (v_i64) atomicOr(&viol[4], 1);
  __syncthreads();
  if (threadIdx.x == 0) {
    int c;
    if (!viol[0] && !viol[4]) c = 4;
    else if (!viol[0]) c = 0;
    else if (!viol[1]) c = 2;
    else if (!viol[2]) c = 3;
    else c = 1;
    *cls = c;
  }
}

__global__ void expand_mask_kernel(const void* __restrict__ tmask, const int* __restrict__ cls,
                                   unsigned char* __restrict__ mask_u8) {
  int n = blockIdx.x * blockDim.x + threadIdx.x;
  if (n >= NPOS) return;
  const int c = *cls;
  int any = 0;
  for (int m = 0; m < MROWS; m++) {
    size_t idx = (size_t)m * NPOS + n;
    int v;
    if (c == 0)      v = ((const int*)tmask)[idx] != 0;
    else if (c == 1) v = ((const unsigned char*)tmask)[idx] != 0;
    else if (c == 2) v = ((const unsigned int*)tmask)[idx] != 0u;
    else if (c == 3) v = ((const unsigned short*)tmask)[idx] != 0u;
    else             v = ((const unsigned long long*)tmask)[idx] != 0ull;
    mask_u8[(m + 1) * NPOS + n] = (unsigned char)v;
    any |= v;
  }
  mask_u8[n] = (unsigned char)any;
}

struct WPtrs { const void* p[4]; };

// Convert Wq/Wk/Wv/Wo to bf16, packed [4][256][256] row-major.
__global__ void conv_w_kernel(WPtrs wp, const int* __restrict__ flags,
                              unsigned short* __restrict__ w_bf) {
  for (int i = blockIdx.x * blockDim.x + threadIdx.x; i < 4 * 65536;
       i += gridDim.x * blockDim.x) {
    int which = i >> 16, off = i & 65535;
    int f = flags[1 + which];
    w_bf[i] = f ? f2b(((const float*)wp.p[which])[off])
                : ((const unsigned short*)wp.p[which])[off];
  }
}

// ---- QKV projection: rows r = s*NPOS + n; out = h @ W^T per projection ----
// Block: 64 rows, 4 waves (wave = 16 rows). MFMA 16x16x32 bf16.
__global__ __launch_bounds__(256) void qkv_kernel(
    const void* __restrict__ h, const int* __restrict__ flags,
    const unsigned short* __restrict__ w_bf,
    unsigned short* __restrict__ q_ws, unsigned short* __restrict__ k_ws,
    unsigned short* __restrict__ v_ws) {
  __shared__ unsigned short As[64 * 264];  // pad +8 bf16: row stride 528B (16B-aligned)
  const int tid = threadIdx.x;
  const size_t R = (size_t)blockIdx.x * 64;
  if (flags[0]) {
    for (int idx = tid; idx < 64 * 64; idx += 256) {
      int r = idx >> 6, c4 = idx & 63;
      float4 v = ((const float4*)h)[(R + r) * 64 + c4];
      unsigned int lo = ((unsigned int)f2b(v.y) << 16) | f2b(v.x);
      unsigned int hi = ((unsigned int)f2b(v.w) << 16) | f2b(v.z);
      *(uint2*)&As[r * 264 + c4 * 4] = make_uint2(lo, hi);
    }
  } else {
    for (int idx = tid; idx < 64 * 32; idx += 256) {
      int r = idx >> 5, c = idx & 31;
      *(uint4*)&As[r * 264 + c * 8] = ((const uint4*)h)[(R + r) * 32 + c];
    }
  }
  __syncthreads();
  const int wave = tid >> 6, lane = tid & 63;
  const int l15 = lane & 15, quad = lane >> 4;
  // A-frag: A[m=l15][k=quad*8+j], contiguous 16B per lane; reused across 3 projections
  bf16x8 af[8];
  #pragma unroll
  for (int t = 0; t < 8; t++)
    af[t] = *(const bf16x8*)&As[(wave * 16 + l15) * 264 + t * 32 + quad * 8];
  #pragma unroll 1
  for (int p = 0; p < 3; p++) {
    const unsigned short* Wp = w_bf + p * 65536;
    f32x4 acc[16];
    #pragma unroll
    for (int j = 0; j < 16; j++) acc[j] = (f32x4){0.f, 0.f, 0.f, 0.f};
    #pragma unroll
    for (int t = 0; t < 8; t++) {
      #pragma unroll
      for (int j = 0; j < 16; j++) {
        // B-frag: B[k][n=l15] = W[n_g][k] row-major, contiguous 16B per lane
        bf16x8 b = *(const bf16x8*)(Wp + (j * 16 + l15) * 256 + t * 32 + quad * 8);
        acc[j] = __builtin_amdgcn_mfma_f32_16x16x32_bf16(af[t], b, acc[j], 0, 0, 0);
      }
    }
    unsigned short* dst = (p == 0) ? q_ws : (p == 1) ? k_ws : v_ws;
    #pragma unroll
    for (int j = 0; j < 16; j++)
      #pragma unroll
      for (int r = 0; r < 4; r++)
        dst[(R + wave * 16 + quad * 4 + r) * 256 + j * 16 + l15] = f2b(acc[j][r]);
  }
}

// ---- Attention per position n: scores + in-register softmax + PV + mask-select ----
__global__ __launch_bounds__(256) void attn_kernel(
    const unsigned short* __restrict__ q_ws, const unsigned short* __restrict__ k_ws,
    const unsigned short* __restrict__ v_ws, const unsigned char* __restrict__ mask_u8,
    unsigned short* __restrict__ o_ws) {
  __shared__ unsigned short qb[S * D], kb[S * D], vb[S * D];
  __shared__ float pmat[S * 160];  // [s][h][20] padded, 16B-aligned rows
  __shared__ unsigned char sm[32];
  const int tid = threadIdx.x;
  const int n = blockIdx.x;
  if (tid < S) sm[tid] = mask_u8[tid * NPOS + n];
  for (int idx = tid; idx < S * 32; idx += 256) {
    int s = idx >> 5, c = idx & 31;
    size_t g = ((size_t)s * NPOS + n) * 32 + c;
    ((uint4*)qb)[idx] = ((const uint4*)q_ws)[g];
    ((uint4*)kb)[idx] = ((const uint4*)k_ws)[g];
    ((uint4*)vb)[idx] = ((const uint4*)v_ws)[g];
  }
  __syncthreads();
  {
    const int hh = tid >> 5, s = tid & 31;
    if (s < S) {
      float qv[32];
      const uint4* qp = (const uint4*)(qb + s * 256 + hh * 32);
      unpack16(qp[0], qp[1], qv);
      unpack16(qp[2], qp[3], qv + 16);
      const float scale = 0.17677669529663687f;  // 1/sqrt(32)
      float sc[S];
      float mx = -3.4e38f;
      #pragma unroll
      for (int t = 0; t < S; t++) {
        const uint4* kp = (const uint4*)(kb + t * 256 + hh * 32);
        float kv[16];
        unpack16(kp[0], kp[1], kv);
        float a = 0.f;
        #pragma unroll
        for (int u = 0; u < 16; u++) a = fmaf(qv[u], kv[u], a);
        unpack16(kp[2], kp[3], kv);
        #pragma unroll
        for (int u = 0; u < 16; u++) a = fmaf(qv[16 + u], kv[u], a);
        a *= scale;
        if (!sm[t]) a -= 1e9f;  // exp underflows to exactly 0 (matches np)
        sc[t] = a;
        mx = fmaxf(mx, a);
      }
      float sum = 0.f;
      #pragma unroll
      for (int t = 0; t < S; t++) { sc[t] = __expf(sc[t] - mx); sum += sc[t]; }
      const float inv = 1.f / sum;
      float* pr = pmat + s * 160 + hh * 20;
      #pragma unroll
      for (int t = 0; t < S; t++) pr[t] = sc[t] * inv;
      pr[17] = 0.f; pr[18] = 0.f; pr[19] = 0.f;
    }
  }
  __syncthreads();
  {
    const int d = tid, hh = d >> 5;
    float vf[S];
    #pragma unroll
    for (int t = 0; t < S; t++) vf[t] = bfu(vb[t * 256 + d]);
    #pragma unroll 1
    for (int s = 0; s < S; s++) {
      const float* pr = pmat + s * 160 + hh * 20;
      float ov = 0.f;
      #pragma unroll
      for (int t = 0; t < S; t++) ov = fmaf(pr[t], vf[t], ov);
      // o = mask ? attn_o : h@Wv^T (vf[s] is exactly the unmasked fallback)
      const float o_val = sm[s] ? ov : vf[s];
      o_ws[((size_t)s * NPOS + n) * 256 + d] = f2b(o_val);
    }
  }
}

// ---- O-projection GEMM + residual(h f32) + bo + LayerNorm, f32 out ----
template <int HF32>
__device__ __forceinline__ void oproj_body(
    const unsigned short* __restrict__ o_ws, const void* __restrict__ h,
    const unsigned short* __restrict__ w_bf, const int* __restrict__ fl,
    const void* __restrict__ bo, const void* __restrict__ lng,
    const void* __restrict__ lnb, float* __restrict__ out,
    unsigned short* As) {
  const int tid = threadIdx.x;
  const size_t R = (size_t)blockIdx.x * 64;
  for (int idx = tid; idx < 64 * 32; idx += 256) {
    int r = idx >> 5, c = idx & 31;
    *(uint4*)&As[r * 264 + c * 8] = ((const uint4*)o_ws)[(R + r) * 32 + c];
  }
  __syncthreads();
  const int wave = tid >> 6, lane = tid & 63;
  const int l15 = lane & 15, quad = lane >> 4;
  bf16x8 af[8];
  #pragma unroll
  for (int t = 0; t < 8; t++)
    af[t] = *(const bf16x8*)&As[(wave * 16 + l15) * 264 + t * 32 + quad * 8];
  const unsigned short* Wp = w_bf + 3 * 65536;
  f32x4 acc[16];
  #pragma unroll
  for (int j = 0; j < 16; j++) acc[j] = (f32x4){0.f, 0.f, 0.f, 0.f};
  #pragma unroll
  for (int t = 0; t < 8; t++) {
    #pragma unroll
    for (int j = 0; j < 16; j++) {
      bf16x8 b = *(const bf16x8*)(Wp + (j * 16 + l15) * 256 + t * 32 + quad * 8);
      acc[j] = __builtin_amdgcn_mfma_f32_16x16x32_bf16(af[t], b, acc[j], 0, 0, 0);
    }
  }
  const int f5 = fl[5], f6 = fl[6], f7 = fl[7];
  float xsum[4] = {0.f, 0.f, 0.f, 0.f}, xsq[4] = {0.f, 0.f, 0.f, 0.f};
  #pragma unroll
  for (int j = 0; j < 16; j++) {
    const int col = j * 16 + l15;
    const float boj = readv(bo, f5, col);
    #pragma unroll
    for (int r = 0; r < 4; r++) {
      const size_t row = R + wave * 16 + quad * 4 + r;
      const float hv = HF32 ? ((const float*)h)[row * 256 + col]
                            : bfu(((const unsigned short*)h)[row * 256 + col]);
      float x = acc[j][r] + hv + boj;
      acc[j][r] = x;
      xsum[r] += x;
      xsq[r] += x * x;
    }
  }
  #pragma unroll
  for (int r = 0; r < 4; r++) {
    #pragma unroll
    for (int m = 1; m <= 8; m <<= 1) {
      xsum[r] += __shfl_xor(xsum[r], m, 64);
      xsq[r]  += __shfl_xor(xsq[r], m, 64);
    }
  }
  float mu[4], rs[4];
  #pragma unroll
  for (int r = 0; r < 4; r++) {
    mu[r] = xsum[r] * (1.0f / 256.0f);
    float var = fmaxf(xsq[r] * (1.0f / 256.0f) - mu[r] * mu[r], 0.0f);
    rs[r] = rsqrtf(var + 1e-5f);
  }
  #pragma unroll
  for (int j = 0; j < 16; j++) {
    const int col = j * 16 + l15;
    const float gj = readv(lng, f6, col);
    const float bj = readv(lnb, f7, col);
    #pragma unroll
    for (int r = 0; r < 4; r++) {
      const size_t row = R + wave * 16 + quad * 4 + r;
      out[row * 256 + col] = (acc[j][r] - mu[r]) * rs[r] * gj + bj;
    }
  }
}

__global__ __launch_bounds__(256) void oproj_ln_kernel(
    const unsigned short* __restrict__ o_ws, const void* __restrict__ h,
    const unsigned short* __restrict__ w_bf, const int* __restrict__ flags,
    const void* __restrict__ bo, const void* __restrict__ lng,
    const void* __restrict__ lnb, float* __restrict__ out) {
  __shared__ unsigned short As[64 * 264];
  if (flags[0]) oproj_body<1>(o_ws, h, w_bf, flags, bo, lng, lnb, out, As);
  else          oproj_body<0>(o_ws, h, w_bf, flags, bo, lng, lnb, out, As);
}

extern "C" void kernel_launch(void* const* d_in, const int* in_sizes, int n_in,
                              void* d_out, int out_size, void* d_ws, size_t ws_size,
                              hipStream_t stream) {
  const void* h     = d_in[0];
  const void* tmask = d_in[1];
  const void* Wq  = d_in[3];
  const void* Wk  = d_in[4];
  const void* Wv  = d_in[5];
  const void* Wo  = d_in[6];
  const void* bo  = d_in[7];
  const void* lng = d_in[8];
  const void* lnb = d_in[9];
  float* out = (float*)d_out;

  char* ws = (char*)d_ws;
  int* mcls  = (int*)ws;                              // @0
  int* flags = (int*)(ws + 64);                       // @64, 8 ints
  unsigned char* mask_u8 = (unsigned char*)(ws + 4096);        // 17*4096 B
  unsigned short* w_bf = (unsigned short*)(ws + 73728);        // 4*65536*2 B
  unsigned short* q_ws = (unsigned short*)(ws + 598016);       // 35651584 B (reused as o)
  unsigned short* k_ws = (unsigned short*)(ws + 598016 + 35651584ull);
  unsigned short* v_ws = (unsigned short*)(ws + 598016 + 2 * 35651584ull);
  unsigned short* o_ws = q_ws;  // safe: block n reads all q[.][n] before writing o[.][n]

  TensorList tl;
  tl.p[0] = (const unsigned short*)h;   tl.n[0] = in_sizes[0];
  tl.p[1] = (const unsigned short*)Wq;  tl.n[1] = in_sizes[3];
  tl.p[2] = (const unsigned short*)Wk;  tl.n[2] = in_sizes[4];
  tl.p[3] = (const unsigned short*)Wv;  tl.n[3] = in_sizes[5];
  tl.p[4] = (const unsigned short*)Wo;  tl.n[4] = in_sizes[6];
  tl.p[5] = (const unsigned short*)bo;  tl.n[5] = in_sizes[7];
  tl.p[6] = (const unsigned short*)lng; tl.n[6] = in_sizes[8];
  tl.p[7] = (const unsigned short*)lnb; tl.n[7] = in_sizes[9];
  WPtrs wp;
  wp.p[0] = Wq; wp.p[1] = Wk; wp.p[2] = Wv; wp.p[3] = Wo;

  detect_multi_kernel<<<8, 256, 0, stream>>>(tl, flags);
  detect_mask_kernel<<<1, 256, 0, stream>>>((const unsigned int*)tmask, mcls);
  expand_mask_kernel<<<NPOS / 256, 256, 0, stream>>>(tmask, mcls, mask_u8);
  conv_w_kernel<<<256, 256, 0, stream>>>(wp, flags, w_bf);
  qkv_kernel<<<S * NPOS / 64, 256, 0, stream>>>(h, flags, w_bf, q_ws, k_ws, v_ws);
  attn_kernel<<<NPOS, 256, 0, stream>>>(q_ws, k_ws, v_ws, mask_u8, o_ws);
  oproj_ln_kernel<<<S * NPOS / 64, 256, 0, stream>>>(o_ws, h, w_bf, flags,
                                                     bo, lng, lnb, out);
}

// Round 7
// 583.383 us; speedup vs baseline: 1.9356x; 1.0970x over previous
//
#include <hip/hip_runtime.h>
#include <hip/hip_bf16.h>

#define S 17
#define NPOS 4096
#define D 256
#define NH 8
#define CH 32
#define MROWS 16

typedef __attribute__((ext_vector_type(8))) short bf16x8;
typedef __attribute__((ext_vector_type(4))) float f32x4;

__device__ __forceinline__ float bfu(unsigned short u) {
  return __uint_as_float(((unsigned int)u) << 16);
}
__device__ __forceinline__ unsigned short f2b(float f) {
  __hip_bfloat16 t = __float2bfloat16(f);
  return *reinterpret_cast<unsigned short*>(&t);
}
__device__ __forceinline__ void unpack16(const uint4 A, const uint4 B, float* r) {
  r[0]  = __uint_as_float(A.x << 16); r[1]  = __uint_as_float(A.x & 0xffff0000u);
  r[2]  = __uint_as_float(A.y << 16); r[3]  = __uint_as_float(A.y & 0xffff0000u);
  r[4]  = __uint_as_float(A.z << 16); r[5]  = __uint_as_float(A.z & 0xffff0000u);
  r[6]  = __uint_as_float(A.w << 16); r[7]  = __uint_as_float(A.w & 0xffff0000u);
  r[8]  = __uint_as_float(B.x << 16); r[9]  = __uint_as_float(B.x & 0xffff0000u);
  r[10] = __uint_as_float(B.y << 16); r[11] = __uint_as_float(B.y & 0xffff0000u);
  r[12] = __uint_as_float(B.z << 16); r[13] = __uint_as_float(B.z & 0xffff0000u);
  r[14] = __uint_as_float(B.w << 16); r[15] = __uint_as_float(B.w & 0xffff0000u);
}
__device__ __forceinline__ float readv(const void* p, int f32, size_t i) {
  return f32 ? ((const float*)p)[i] : bfu(((const unsigned short*)p)[i]);
}

struct TensorList {
  const unsigned short* p[8];
  int n[8];
};

// Per-tensor dtype detection. flags[b]=1 -> f32 storage, 0 -> bf16 storage. (proven r5)
__global__ void detect_multi_kernel(TensorList tl, int* __restrict__ flags) {
  __shared__ int s_totnz, s_evnz, s_evwild;
  if (threadIdx.x == 0) { s_totnz = 0; s_evnz = 0; s_evwild = 0; }
  __syncthreads();
  const unsigned short* p = tl.p[blockIdx.x];
  const int n = tl.n[blockIdx.x];
  const int w = n < 4096 ? n : 4096;
  int totnz = 0, evnz = 0, evwild = 0;
  for (int i = threadIdx.x; i < w; i += blockDim.x) {
    unsigned short u = p[i];
    if (u) {
      totnz++;
      if (!(i & 1)) {
        evnz++;
        int e = (u >> 7) & 0xFF;
        if (e == 0 || e == 255 || e < 97 || e > 157) evwild++;
      }
    }
  }
  atomicAdd(&s_totnz, totnz);
  atomicAdd(&s_evnz, evnz);
  atomicAdd(&s_evwild, evwild);
  __syncthreads();
  if (threadIdx.x == 0) {
    const int evcount = w / 2;
    int f;
    if (s_totnz == 0) f = 0;
    else if (s_evnz == 0) f = 1;
    else if (s_evwild * 8 > evcount) f = 1;
    else f = 0;
    flags[blockIdx.x] = f;
  }
}

// mask dtype classification: 0=i32, 1=u8, 2=f32, 3=bf16, 4=i64 (proven r5)
__global__ void detect_mask_kernel(const unsigned int* __restrict__ w,
                                   int* __restrict__ cls) {
  __shared__ int viol[5];
  if (threadIdx.x < 5) viol[threadIdx.x] = 0;
  __syncthreads();
  int v_i32 = 0, v_f32 = 0, v_bf16 = 0, v_u8 = 0, v_i64 = 0;
  const int nwords = 65536 / 4;
  for (int i = threadIdx.x; i < nwords; i += blockDim.x) {
    unsigned int x = w[i];
    if (x > 1u) v_i32 = 1;
    if (x != 0u && x != 0x3F800000u) v_f32 = 1;
    unsigned int lo = x & 0xFFFFu, hi = x >> 16;
    if ((lo != 0u && lo != 0x3F80u) || (hi != 0u && hi != 0x3F80u)) v_bf16 = 1;
    if ((x & 0xFEFEFEFEu) != 0u) v_u8 = 1;
    if ((i & 1) && x != 0u) v_i64 = 1;
  }
  if (v_i32) atomicOr(&viol[0], 1);
  if (v_f32) atomicOr(&viol[1], 1);
  if (v_bf16) atomicOr(&viol[2], 1);
  if (v_u8) atomicOr(&viol[3], 1);
  if (v_i64) atomicOr(&viol[4], 1);
  __syncthreads();
  if (threadIdx.x == 0) {
    int c;
    if (!viol[0] && !viol[4]) c = 4;
    else if (!viol[0]) c = 0;
    else if (!viol[1]) c = 2;
    else if (!viol[2]) c = 3;
    else c = 1;
    *cls = c;
  }
}

__global__ void expand_mask_kernel(const void* __restrict__ tmask, const int* __restrict__ cls,
                                   unsigned char* __restrict__ mask_u8) {
  int n = blockIdx.x * blockDim.x + threadIdx.x;
  if (n >= NPOS) return;
  const int c = *cls;
  int any = 0;
  for (int m = 0; m < MROWS; m++) {
    size_t idx = (size_t)m * NPOS + n;
    int v;
    if (c == 0)      v = ((const int*)tmask)[idx] != 0;
    else if (c == 1) v = ((const unsigned char*)tmask)[idx] != 0;
    else if (c == 2) v = ((const unsigned int*)tmask)[idx] != 0u;
    else if (c == 3) v = ((const unsigned short*)tmask)[idx] != 0u;
    else             v = ((const unsigned long long*)tmask)[idx] != 0ull;
    mask_u8[(m + 1) * NPOS + n] = (unsigned char)v;
    any |= v;
  }
  mask_u8[n] = (unsigned char)any;
}

struct WPtrs { const void* p[4]; };

__global__ void conv_w_kernel(WPtrs wp, const int* __restrict__ flags,
                              unsigned short* __restrict__ w_bf) {
  for (int i = blockIdx.x * blockDim.x + threadIdx.x; i < 4 * 65536;
       i += gridDim.x * blockDim.x) {
    int which = i >> 16, off = i & 65535;
    int f = flags[1 + which];
    w_bf[i] = f ? f2b(((const float*)wp.p[which])[off])
                : ((const unsigned short*)wp.p[which])[off];
  }
}

// ---- QKV projection, M=128 rows/block, wave = 32 rows (2 m-tiles) ----
// Each B-frag load feeds 2 MFMAs; acc[2][16]+af[2][8] force a deep-ILP schedule.
__global__ __launch_bounds__(256) void qkv_kernel(
    const void* __restrict__ h, const int* __restrict__ flags,
    const unsigned short* __restrict__ w_bf,
    unsigned short* __restrict__ q_ws, unsigned short* __restrict__ k_ws,
    unsigned short* __restrict__ v_ws) {
  __shared__ unsigned short As[128 * 264];  // 67.6 KB, row stride 528 B (16B-aligned)
  const int tid = threadIdx.x;
  const size_t R = (size_t)blockIdx.x * 128;
  if (flags[0]) {
    for (int idx = tid; idx < 128 * 64; idx += 256) {
      int r = idx >> 6, c4 = idx & 63;
      float4 v = ((const float4*)h)[(R + r) * 64 + c4];
      unsigned int lo = ((unsigned int)f2b(v.y) << 16) | f2b(v.x);
      unsigned int hi = ((unsigned int)f2b(v.w) << 16) | f2b(v.z);
      *(uint2*)&As[r * 264 + c4 * 4] = make_uint2(lo, hi);
    }
  } else {
    for (int idx = tid; idx < 128 * 32; idx += 256) {
      int r = idx >> 5, c = idx & 31;
      *(uint4*)&As[r * 264 + c * 8] = ((const uint4*)h)[(R + r) * 32 + c];
    }
  }
  __syncthreads();
  const int wave = tid >> 6, lane = tid & 63;
  const int l15 = lane & 15, quad = lane >> 4;
  // A-frags for 2 m-tiles (rows wave*32 + {0..15, 16..31}), reused across 3 projections
  bf16x8 af0[8], af1[8];
  #pragma unroll
  for (int t = 0; t < 8; t++) {
    af0[t] = *(const bf16x8*)&As[(wave * 32 + l15) * 264 + t * 32 + quad * 8];
    af1[t] = *(const bf16x8*)&As[(wave * 32 + 16 + l15) * 264 + t * 32 + quad * 8];
  }
  #pragma unroll 1
  for (int p = 0; p < 3; p++) {
    const unsigned short* Wp = w_bf + p * 65536;
    f32x4 acc0[16], acc1[16];
    #pragma unroll
    for (int j = 0; j < 16; j++) {
      acc0[j] = (f32x4){0.f, 0.f, 0.f, 0.f};
      acc1[j] = (f32x4){0.f, 0.f, 0.f, 0.f};
    }
    #pragma unroll
    for (int t = 0; t < 8; t++) {
      #pragma unroll
      for (int j = 0; j < 16; j++) {
        bf16x8 b = *(const bf16x8*)(Wp + (j * 16 + l15) * 256 + t * 32 + quad * 8);
        acc0[j] = __builtin_amdgcn_mfma_f32_16x16x32_bf16(af0[t], b, acc0[j], 0, 0, 0);
        acc1[j] = __builtin_amdgcn_mfma_f32_16x16x32_bf16(af1[t], b, acc1[j], 0, 0, 0);
      }
    }
    unsigned short* dst = (p == 0) ? q_ws : (p == 1) ? k_ws : v_ws;
    #pragma unroll
    for (int j = 0; j < 16; j++)
      #pragma unroll
      for (int r = 0; r < 4; r++) {
        dst[(R + wave * 32 + quad * 4 + r) * 256 + j * 16 + l15] = f2b(acc0[j][r]);
        dst[(R + wave * 32 + 16 + quad * 4 + r) * 256 + j * 16 + l15] = f2b(acc1[j][r]);
      }
  }
}

// ---- Attention per position n (unchanged from r6; validated) ----
__global__ __launch_bounds__(256) void attn_kernel(
    const unsigned short* __restrict__ q_ws, const unsigned short* __restrict__ k_ws,
    const unsigned short* __restrict__ v_ws, const unsigned char* __restrict__ mask_u8,
    unsigned short* __restrict__ o_ws) {
  __shared__ unsigned short qb[S * D], kb[S * D], vb[S * D];
  __shared__ float pmat[S * 160];
  __shared__ unsigned char sm[32];
  const int tid = threadIdx.x;
  const int n = blockIdx.x;
  if (tid < S) sm[tid] = mask_u8[tid * NPOS + n];
  for (int idx = tid; idx < S * 32; idx += 256) {
    int s = idx >> 5, c = idx & 31;
    size_t g = ((size_t)s * NPOS + n) * 32 + c;
    ((uint4*)qb)[idx] = ((const uint4*)q_ws)[g];
    ((uint4*)kb)[idx] = ((const uint4*)k_ws)[g];
    ((uint4*)vb)[idx] = ((const uint4*)v_ws)[g];
  }
  __syncthreads();
  {
    const int hh = tid >> 5, s = tid & 31;
    if (s < S) {
      float qv[32];
      const uint4* qp = (const uint4*)(qb + s * 256 + hh * 32);
      unpack16(qp[0], qp[1], qv);
      unpack16(qp[2], qp[3], qv + 16);
      const float scale = 0.17677669529663687f;  // 1/sqrt(32)
      float sc[S];
      float mx = -3.4e38f;
      #pragma unroll
      for (int t = 0; t < S; t++) {
        const uint4* kp = (const uint4*)(kb + t * 256 + hh * 32);
        float kv[16];
        unpack16(kp[0], kp[1], kv);
        float a = 0.f;
        #pragma unroll
        for (int u = 0; u < 16; u++) a = fmaf(qv[u], kv[u], a);
        unpack16(kp[2], kp[3], kv);
        #pragma unroll
        for (int u = 0; u < 16; u++) a = fmaf(qv[16 + u], kv[u], a);
        a *= scale;
        if (!sm[t]) a -= 1e9f;  // exp underflows to exactly 0 (matches np)
        sc[t] = a;
        mx = fmaxf(mx, a);
      }
      float sum = 0.f;
      #pragma unroll
      for (int t = 0; t < S; t++) { sc[t] = __expf(sc[t] - mx); sum += sc[t]; }
      const float inv = 1.f / sum;
      float* pr = pmat + s * 160 + hh * 20;
      #pragma unroll
      for (int t = 0; t < S; t++) pr[t] = sc[t] * inv;
      pr[17] = 0.f; pr[18] = 0.f; pr[19] = 0.f;
    }
  }
  __syncthreads();
  {
    const int d = tid, hh = d >> 5;
    float vf[S];
    #pragma unroll
    for (int t = 0; t < S; t++) vf[t] = bfu(vb[t * 256 + d]);
    #pragma unroll 1
    for (int s = 0; s < S; s++) {
      const float* pr = pmat + s * 160 + hh * 20;
      float ov = 0.f;
      #pragma unroll
      for (int t = 0; t < S; t++) ov = fmaf(pr[t], vf[t], ov);
      const float o_val = sm[s] ? ov : vf[s];
      o_ws[((size_t)s * NPOS + n) * 256 + d] = f2b(o_val);
    }
  }
}

// ---- O-projection (M=128) + residual + bo + LayerNorm, f32 out ----
template <int HF32>
__device__ __forceinline__ void oproj_body(
    const unsigned short* __restrict__ o_ws, const void* __restrict__ h,
    const unsigned short* __restrict__ w_bf, const int* __restrict__ fl,
    const void* __restrict__ bo, const void* __restrict__ lng,
    const void* __restrict__ lnb, float* __restrict__ out,
    unsigned short* As) {
  const int tid = threadIdx.x;
  const size_t R = (size_t)blockIdx.x * 128;
  for (int idx = tid; idx < 128 * 32; idx += 256) {
    int r = idx >> 5, c = idx & 31;
    *(uint4*)&As[r * 264 + c * 8] = ((const uint4*)o_ws)[(R + r) * 32 + c];
  }
  __syncthreads();
  const int wave = tid >> 6, lane = tid & 63;
  const int l15 = lane & 15, quad = lane >> 4;
  bf16x8 af0[8], af1[8];
  #pragma unroll
  for (int t = 0; t < 8; t++) {
    af0[t] = *(const bf16x8*)&As[(wave * 32 + l15) * 264 + t * 32 + quad * 8];
    af1[t] = *(const bf16x8*)&As[(wave * 32 + 16 + l15) * 264 + t * 32 + quad * 8];
  }
  const unsigned short* Wp = w_bf + 3 * 65536;
  f32x4 acc0[16], acc1[16];
  #pragma unroll
  for (int j = 0; j < 16; j++) {
    acc0[j] = (f32x4){0.f, 0.f, 0.f, 0.f};
    acc1[j] = (f32x4){0.f, 0.f, 0.f, 0.f};
  }
  #pragma unroll
  for (int t = 0; t < 8; t++) {
    #pragma unroll
    for (int j = 0; j < 16; j++) {
      bf16x8 b = *(const bf16x8*)(Wp + (j * 16 + l15) * 256 + t * 32 + quad * 8);
      acc0[j] = __builtin_amdgcn_mfma_f32_16x16x32_bf16(af0[t], b, acc0[j], 0, 0, 0);
      acc1[j] = __builtin_amdgcn_mfma_f32_16x16x32_bf16(af1[t], b, acc1[j], 0, 0, 0);
    }
  }
  const int f5 = fl[5], f6 = fl[6], f7 = fl[7];
  float xsum0[4] = {0, 0, 0, 0}, xsq0[4] = {0, 0, 0, 0};
  float xsum1[4] = {0, 0, 0, 0}, xsq1[4] = {0, 0, 0, 0};
  #pragma unroll
  for (int j = 0; j < 16; j++) {
    const int col = j * 16 + l15;
    const float boj = readv(bo, f5, col);
    #pragma unroll
    for (int r = 0; r < 4; r++) {
      const size_t row0 = R + wave * 32 + quad * 4 + r;
      const size_t row1 = row0 + 16;
      float h0 = HF32 ? ((const float*)h)[row0 * 256 + col]
                      : bfu(((const unsigned short*)h)[row0 * 256 + col]);
      float h1 = HF32 ? ((const float*)h)[row1 * 256 + col]
                      : bfu(((const unsigned short*)h)[row1 * 256 + col]);
      float x0 = acc0[j][r] + h0 + boj;
      float x1 = acc1[j][r] + h1 + boj;
      acc0[j][r] = x0; acc1[j][r] = x1;
      xsum0[r] += x0; xsq0[r] += x0 * x0;
      xsum1[r] += x1; xsq1[r] += x1 * x1;
    }
  }
  #pragma unroll
  for (int r = 0; r < 4; r++) {
    #pragma unroll
    for (int m = 1; m <= 8; m <<= 1) {
      xsum0[r] += __shfl_xor(xsum0[r], m, 64);
      xsq0[r]  += __shfl_xor(xsq0[r], m, 64);
      xsum1[r] += __shfl_xor(xsum1[r], m, 64);
      xsq1[r]  += __shfl_xor(xsq1[r], m, 64);
    }
  }
  float mu0[4], rs0[4], mu1[4], rs1[4];
  #pragma unroll
  for (int r = 0; r < 4; r++) {
    mu0[r] = xsum0[r] * (1.0f / 256.0f);
    rs0[r] = rsqrtf(fmaxf(xsq0[r] * (1.0f / 256.0f) - mu0[r] * mu0[r], 0.0f) + 1e-5f);
    mu1[r] = xsum1[r] * (1.0f / 256.0f);
    rs1[r] = rsqrtf(fmaxf(xsq1[r] * (1.0f / 256.0f) - mu1[r] * mu1[r], 0.0f) + 1e-5f);
  }
  #pragma unroll
  for (int j = 0; j < 16; j++) {
    const int col = j * 16 + l15;
    const float gj = readv(lng, f6, col);
    const float bj = readv(lnb, f7, col);
    #pragma unroll
    for (int r = 0; r < 4; r++) {
      const size_t row0 = R + wave * 32 + quad * 4 + r;
      out[row0 * 256 + col] = (acc0[j][r] - mu0[r]) * rs0[r] * gj + bj;
      out[(row0 + 16) * 256 + col] = (acc1[j][r] - mu1[r]) * rs1[r] * gj + bj;
    }
  }
}

__global__ __launch_bounds__(256) void oproj_ln_kernel(
    const unsigned short* __restrict__ o_ws, const void* __restrict__ h,
    const unsigned short* __restrict__ w_bf, const int* __restrict__ flags,
    const void* __restrict__ bo, const void* __restrict__ lng,
    const void* __restrict__ lnb, float* __restrict__ out) {
  __shared__ unsigned short As[128 * 264];
  if (flags[0]) oproj_body<1>(o_ws, h, w_bf, flags, bo, lng, lnb, out, As);
  else          oproj_body<0>(o_ws, h, w_bf, flags, bo, lng, lnb, out, As);
}

extern "C" void kernel_launch(void* const* d_in, const int* in_sizes, int n_in,
                              void* d_out, int out_size, void* d_ws, size_t ws_size,
                              hipStream_t stream) {
  const void* h     = d_in[0];
  const void* tmask = d_in[1];
  const void* Wq  = d_in[3];
  const void* Wk  = d_in[4];
  const void* Wv  = d_in[5];
  const void* Wo  = d_in[6];
  const void* bo  = d_in[7];
  const void* lng = d_in[8];
  const void* lnb = d_in[9];
  float* out = (float*)d_out;

  char* ws = (char*)d_ws;
  int* mcls  = (int*)ws;
  int* flags = (int*)(ws + 64);
  unsigned char* mask_u8 = (unsigned char*)(ws + 4096);
  unsigned short* w_bf = (unsigned short*)(ws + 73728);
  unsigned short* q_ws = (unsigned short*)(ws + 598016);
  unsigned short* k_ws = (unsigned short*)(ws + 598016 + 35651584ull);
  unsigned short* v_ws = (unsigned short*)(ws + 598016 + 2 * 35651584ull);
  unsigned short* o_ws = q_ws;  // safe: block n reads all q[.][n] before writing o[.][n]

  TensorList tl;
  tl.p[0] = (const unsigned short*)h;   tl.n[0] = in_sizes[0];
  tl.p[1] = (const unsigned short*)Wq;  tl.n[1] = in_sizes[3];
  tl.p[2] = (const unsigned short*)Wk;  tl.n[2] = in_sizes[4];
  tl.p[3] = (const unsigned short*)Wv;  tl.n[3] = in_sizes[5];
  tl.p[4] = (const unsigned short*)Wo;  tl.n[4] = in_sizes[6];
  tl.p[5] = (const unsigned short*)bo;  tl.n[5] = in_sizes[7];
  tl.p[6] = (const unsigned short*)lng; tl.n[6] = in_sizes[8];
  tl.p[7] = (const unsigned short*)lnb; tl.n[7] = in_sizes[9];
  WPtrs wp;
  wp.p[0] = Wq; wp.p[1] = Wk; wp.p[2] = Wv; wp.p[3] = Wo;

  detect_multi_kernel<<<8, 256, 0, stream>>>(tl, flags);
  detect_mask_kernel<<<1, 256, 0, stream>>>((const unsigned int*)tmask, mcls);
  expand_mask_kernel<<<NPOS / 256, 256, 0, stream>>>(tmask, mcls, mask_u8);
  conv_w_kernel<<<256, 256, 0, stream>>>(wp, flags, w_bf);
  qkv_kernel<<<S * NPOS / 128, 256, 0, stream>>>(h, flags, w_bf, q_ws, k_ws, v_ws);
  attn_kernel<<<NPOS, 256, 0, stream>>>(q_ws, k_ws, v_ws, mask_u8, o_ws);
  oproj_ln_kernel<<<S * NPOS / 128, 256, 0, stream>>>(o_ws, h, w_bf, flags,
                                                      bo, lng, lnb, out);
}